// Round 3
// baseline (71.856 us; speedup 1.0000x reference)
//
#include <hip/hip_runtime.h>
#include <hip/hip_fp16.h>

typedef _Float16 half8 __attribute__((ext_vector_type(8)));
typedef float float4v __attribute__((ext_vector_type(4)));

#define E_DIM 300
#define KP 320               // padded K (10 MFMA k-steps of 32)
#define B_ 32
#define NROW_CDD 3200        // 32*5*20
#define NROW_HIS 32000       // 32*50*20
#define NCHUNK 25            // 2 h per chunk

// ---------------- Kernel 1: gather + l2-normalize -> fp16 rows (K padded to 320) --------
__global__ __launch_bounds__(256) void gather_norm(const int* __restrict__ cand,
                                                   const int* __restrict__ clk,
                                                   const float* __restrict__ emb,
                                                   _Float16* __restrict__ outH)
{
    int row  = blockIdx.x * 4 + (threadIdx.x >> 6);
    int lane = threadIdx.x & 63;
    int tok = (row < NROW_CDD) ? cand[row] : clk[row - NROW_CDD];
    const float* e = emb + (long)tok * E_DIM;
    float v[5];
    float ss = 0.f;
#pragma unroll
    for (int j = 0; j < 5; ++j) {
        int idx = lane + j * 64;
        float x = (idx < E_DIM) ? e[idx] : 0.f;
        v[j] = x;
        ss += x * x;
    }
#pragma unroll
    for (int off = 32; off; off >>= 1) ss += __shfl_xor(ss, off);
    float scale = 1.0f / fmaxf(sqrtf(ss), 1e-12f);
    _Float16* o = outH + (long)row * KP;
#pragma unroll
    for (int j = 0; j < 5; ++j) {
        int idx = lane + j * 64;
        o[idx] = (_Float16)((idx < E_DIM) ? v[j] * scale : 0.f);
    }
}

// ---------------- Kernel 2: fused sim-GEMM (MFMA, LDS sim tile) + gaussian pooling ------
// grid (NCHUNK=25, B_=32) = 800 blocks, 256 threads. LDS ~17.5 KB -> fully resident grid.
__global__ __launch_bounds__(256) void knrm_fused(const _Float16* __restrict__ wsH,
                                                  const float* __restrict__ cpad,
                                                  const float* __restrict__ hpad,
                                                  const float* __restrict__ ltr_w,
                                                  float* __restrict__ partial)
{
    __shared__ float simS[100 * 41];   // sim tile, stride 41 (41%32=9, conflict-free)
    __shared__ float hpS[40];
    __shared__ float wvS[40];
    __shared__ float svals[200];

    int b = blockIdx.y, chunk = blockIdx.x;
    int tid = threadIdx.x;
    int wave = tid >> 6, lane = tid & 63;
    int g = lane >> 4, r16 = lane & 15;

    if (tid < 40) {
        hpS[tid] = hpad[b * 1000 + chunk * 40 + tid];
        wvS[tid] = ltr_w[chunk * 40 + tid];
    }

    // ---- Phase 1: 100x40 sim tile via MFMA, fragments straight from global (L2-hot) ----
    const char* gA = (const char*)(wsH + (size_t)b * 100 * KP);
    const char* gB = (const char*)(wsH + (size_t)NROW_CDD * KP + (size_t)b * 1000 * KP);

    float4v acc[2][3];
#pragma unroll
    for (int mi = 0; mi < 2; ++mi)
#pragma unroll
        for (int n = 0; n < 3; ++n) acc[mi][n] = (float4v){0.f, 0.f, 0.f, 0.f};

#pragma unroll 2
    for (int k = 0; k < 10; ++k) {
        half8 bf[3];
#pragma unroll
        for (int n = 0; n < 3; ++n) {
            int rL = chunk * 40 + n * 16 + r16;
            if (rL > 999) rL = 999;                       // clamp inside this b
            bf[n] = *(const half8*)(gB + (size_t)rL * 640 + k * 64 + g * 16);
        }
#pragma unroll
        for (int mi = 0; mi < 2; ++mi) {
            int m = wave * 2 + mi;
            if (m < 7) {
                int rA = m * 16 + r16; if (rA > 99) rA = 99;
                half8 af = *(const half8*)(gA + (size_t)rA * 640 + k * 64 + g * 16);
#pragma unroll
                for (int n = 0; n < 3; ++n)
                    acc[mi][n] = __builtin_amdgcn_mfma_f32_16x16x32_f16(af, bf[n], acc[mi][n], 0, 0, 0);
            }
        }
    }
    // C/D layout (m89-verified): col = lane&15 (B-row), row = (lane>>4)*4+j (A-row)
#pragma unroll
    for (int mi = 0; mi < 2; ++mi) {
        int m = wave * 2 + mi;
        if (m < 7) {
#pragma unroll
            for (int n = 0; n < 3; ++n) {
                int col = n * 16 + r16;
                if (col < 40) {
#pragma unroll
                    for (int j = 0; j < 4; ++j) {
                        int row = m * 16 + g * 4 + j;
                        if (row < 100) simS[row * 41 + col] = acc[mi][n][j];
                    }
                }
            }
        }
    }
    __syncthreads();

    // ---- Phase 2: gaussian kernels + log pooling. thread = (hl, cdd-row) ----
    float val = 0.f;
    int hl = tid / 100, row = tid % 100;
    if (tid < 200) {
        float s[20], mmv[20];
#pragma unroll
        for (int t = 0; t < 20; ++t) {
            s[t]   = simS[row * 41 + hl * 20 + t];
            mmv[t] = hpS[hl * 20 + t];
        }
        const float L2E = 1.44269504f;
        for (int k = 0; k < 20; ++k) {
            float mu = -0.9f + 0.1f * (float)k;
            float ce = (k == 19) ? (-500000.0f * L2E) : (-50.0f * L2E);
            float psum = 0.f;
#pragma unroll
            for (int t = 0; t < 20; ++t) {
                float d = s[t] - mu;
                psum += exp2f(d * d * ce) * mmv[t];
            }
            val += __logf(fmaxf(psum, 1e-10f)) * wvS[hl * 20 + k];
        }
        val *= 0.01f * cpad[b * 100 + row];
        svals[row * 2 + hl] = val;
    }
    __syncthreads();

    // ---- per-candidate partial for this chunk ----
    if (tid < 5) {
        float ssum = 0.f;
#pragma unroll
        for (int i = 0; i < 40; ++i) ssum += svals[tid * 40 + i];
        partial[(b * 5 + tid) * NCHUNK + chunk] = ssum;
    }
}

// ---------------- Kernel 3: sum chunks + bias + log_softmax over C=5 --------------------
__global__ __launch_bounds__(64) void finalize(const float* __restrict__ partial,
                                               const float* __restrict__ ltr_b,
                                               float* __restrict__ out)
{
    int b = blockIdx.x;
    int tid = threadIdx.x;
    __shared__ float sc[5];
    if (tid < 5) {
        float a = ltr_b[0];
        const float* pp = partial + (b * 5 + tid) * NCHUNK;
#pragma unroll
        for (int ch = 0; ch < NCHUNK; ++ch) a += pp[ch];
        sc[tid] = a;
    }
    __syncthreads();
    if (tid < 5) {
        float m = fmaxf(fmaxf(fmaxf(sc[0], sc[1]), fmaxf(sc[2], sc[3])), sc[4]);
        float sum = 0.f;
#pragma unroll
        for (int i = 0; i < 5; ++i) sum += __expf(sc[i] - m);
        out[b * 5 + tid] = sc[tid] - m - __logf(sum);
    }
}

extern "C" void kernel_launch(void* const* d_in, const int* in_sizes, int n_in,
                              void* d_out, int out_size, void* d_ws, size_t ws_size,
                              hipStream_t stream)
{
    const int*   cand = (const int*)d_in[0];
    const int*   clk  = (const int*)d_in[1];
    const float* cpad = (const float*)d_in[2];
    const float* hpad = (const float*)d_in[3];
    const float* emb  = (const float*)d_in[4];
    const float* lw   = (const float*)d_in[5];
    const float* lb   = (const float*)d_in[6];
    float* out = (float*)d_out;

    _Float16* wsH  = (_Float16*)d_ws;                                                    // 22.528 MB
    float* partial = (float*)((char*)d_ws + (size_t)(NROW_CDD + NROW_HIS) * KP * 2);     // 16 KB

    hipLaunchKernelGGL(gather_norm, dim3((NROW_CDD + NROW_HIS) / 4), dim3(256), 0, stream,
                       cand, clk, emb, wsH);
    hipLaunchKernelGGL(knrm_fused, dim3(NCHUNK, B_), dim3(256), 0, stream,
                       wsH, cpad, hpad, lw, partial);
    hipLaunchKernelGGL(finalize, dim3(B_), dim3(64), 0, stream, partial, lb, out);
}

// Round 4
// 54.760 us; speedup vs baseline: 1.3122x; 1.3122x over previous
//
#include <hip/hip_runtime.h>
#include <hip/hip_fp16.h>

typedef _Float16 half8 __attribute__((ext_vector_type(8)));
typedef float float4v __attribute__((ext_vector_type(4)));

#define E_DIM 300
#define KP 320               // padded K (10 MFMA k-steps of 32)
#define B_ 32
#define NROW_CDD 3200        // 32*5*20
#define NROW_HIS 32000       // 32*50*20
#define NCHUNK 25            // 2 h per chunk

#if __has_builtin(__builtin_amdgcn_exp2f)
#define EXP2(x) __builtin_amdgcn_exp2f(x)
#else
#define EXP2(x) exp2f(x)
#endif
#if __has_builtin(__builtin_amdgcn_logf)
#define LOG2(x) __builtin_amdgcn_logf(x)
#else
#define LOG2(x) log2f(x)
#endif

// ---------------- Kernel 1: gather + l2-normalize -> fp16 rows (K padded to 320) --------
__global__ __launch_bounds__(256) void gather_norm(const int* __restrict__ cand,
                                                   const int* __restrict__ clk,
                                                   const float* __restrict__ emb,
                                                   _Float16* __restrict__ outH)
{
    int row  = blockIdx.x * 4 + (threadIdx.x >> 6);
    int lane = threadIdx.x & 63;
    int tok = (row < NROW_CDD) ? cand[row] : clk[row - NROW_CDD];
    const float* e = emb + (long)tok * E_DIM;
    float v[5];
    float ss = 0.f;
#pragma unroll
    for (int j = 0; j < 5; ++j) {
        int idx = lane + j * 64;
        float x = (idx < E_DIM) ? e[idx] : 0.f;
        v[j] = x;
        ss += x * x;
    }
#pragma unroll
    for (int off = 32; off; off >>= 1) ss += __shfl_xor(ss, off);
    float scale = 1.0f / fmaxf(sqrtf(ss), 1e-12f);
    _Float16* o = outH + (long)row * KP;
#pragma unroll
    for (int j = 0; j < 5; ++j) {
        int idx = lane + j * 64;
        o[idx] = (_Float16)((idx < E_DIM) ? v[j] * scale : 0.f);
    }
}

// ---------------- Kernel 2: fused sim-GEMM (MFMA, LDS sim tile) + gaussian pooling ------
// grid (NCHUNK=25, B_=32) = 800 blocks, 256 threads. LDS ~17.5 KB.
__global__ __launch_bounds__(256) void knrm_fused(const _Float16* __restrict__ wsH,
                                                  const float* __restrict__ cpad,
                                                  const float* __restrict__ hpad,
                                                  const float* __restrict__ ltr_w,
                                                  float* __restrict__ partial)
{
    __shared__ float simS[100 * 41];   // sim tile, stride 41 (conflict-free)
    __shared__ float hpS[40];
    __shared__ float wvS[40];
    __shared__ float svals[200];

    int b = blockIdx.y, chunk = blockIdx.x;
    int tid = threadIdx.x;
    int wave = tid >> 6, lane = tid & 63;
    int g = lane >> 4, r16 = lane & 15;

    if (tid < 40) {
        hpS[tid] = hpad[b * 1000 + chunk * 40 + tid];
        wvS[tid] = ltr_w[chunk * 40 + tid];
    }

    // ---- Phase 1: 100x40 sim tile via MFMA, fragments straight from global (L2-hot) ----
    const char* gA = (const char*)(wsH + (size_t)b * 100 * KP);
    const char* gB = (const char*)(wsH + (size_t)NROW_CDD * KP + (size_t)b * 1000 * KP);

    float4v acc[2][3];
#pragma unroll
    for (int mi = 0; mi < 2; ++mi)
#pragma unroll
        for (int n = 0; n < 3; ++n) acc[mi][n] = (float4v){0.f, 0.f, 0.f, 0.f};

#pragma unroll 2
    for (int k = 0; k < 10; ++k) {
        half8 bf[3];
#pragma unroll
        for (int n = 0; n < 3; ++n) {
            int rL = chunk * 40 + n * 16 + r16;
            if (rL > 999) rL = 999;
            bf[n] = *(const half8*)(gB + (size_t)rL * 640 + k * 64 + g * 16);
        }
#pragma unroll
        for (int mi = 0; mi < 2; ++mi) {
            int m = wave * 2 + mi;
            if (m < 7) {
                int rA = m * 16 + r16; if (rA > 99) rA = 99;
                half8 af = *(const half8*)(gA + (size_t)rA * 640 + k * 64 + g * 16);
#pragma unroll
                for (int n = 0; n < 3; ++n)
                    acc[mi][n] = __builtin_amdgcn_mfma_f32_16x16x32_f16(af, bf[n], acc[mi][n], 0, 0, 0);
            }
        }
    }
    // C/D layout (m89-verified): col = lane&15 (B-row), row = (lane>>4)*4+j (A-row)
#pragma unroll
    for (int mi = 0; mi < 2; ++mi) {
        int m = wave * 2 + mi;
        if (m < 7) {
#pragma unroll
            for (int n = 0; n < 3; ++n) {
                int col = n * 16 + r16;
                if (col < 40) {
#pragma unroll
                    for (int j = 0; j < 4; ++j) {
                        int row = m * 16 + g * 4 + j;
                        if (row < 100) simS[row * 41 + col] = acc[mi][n][j];
                    }
                }
            }
        }
    }
    __syncthreads();

    // ---- Phase 2: gaussian kernels + log pooling, t-outer / k-inner, psum[20] in regs ----
    const float CE   = -72.13475204f;     // -50 * log2(e)
    const float CE19 = -721347.52f;       // -500000 * log2(e)

    int hl = tid >> 7 ? 1 : (tid >= 100 ? 1 : 0);   // placeholder, recomputed below
    (void)hl;
    int unit_h = tid / 100;          // 0 or 1 (for tid<200)
    int row = tid - unit_h * 100;

    float psum[20];
#pragma unroll
    for (int k = 0; k < 20; ++k) psum[k] = 0.f;

    if (tid < 200) {
        const float* sp = simS + row * 41 + unit_h * 20;
        const float* mp = hpS + unit_h * 20;
#pragma unroll 4
        for (int t = 0; t < 20; ++t) {
            float s  = sp[t];
            float mm = mp[t];
            float a  = CE * s * s;
#pragma unroll
            for (int k = 0; k < 19; ++k) {
                const float mu = -0.9f + 0.1f * (float)k;
                const float bk = -2.0f * CE * mu;
                const float ck = CE * mu * mu;
                float arg = fmaf(bk, s, a + ck);
                psum[k] = fmaf(EXP2(arg), mm, psum[k]);
            }
            float d = s - 1.0f;
            psum[19] = fmaf(EXP2(CE19 * d * d), mm, psum[19]);
        }
        float val = 0.f;
#pragma unroll
        for (int k = 0; k < 20; ++k)
            val += LOG2(fmaxf(psum[k], 1e-10f)) * wvS[unit_h * 20 + k];
        // natural-log + 0.01 scale folded: ln(x)=log2(x)*ln2
        val *= 0.0069314718f * cpad[b * 100 + row];
        svals[row * 2 + unit_h] = val;
    }
    __syncthreads();

    // ---- per-candidate partial for this chunk ----
    if (tid < 5) {
        float ssum = 0.f;
#pragma unroll
        for (int i = 0; i < 40; ++i) ssum += svals[tid * 40 + i];
        partial[(b * 5 + tid) * NCHUNK + chunk] = ssum;
    }
}

// ---------------- Kernel 3: sum chunks + bias + log_softmax over C=5 --------------------
__global__ __launch_bounds__(64) void finalize(const float* __restrict__ partial,
                                               const float* __restrict__ ltr_b,
                                               float* __restrict__ out)
{
    int b = blockIdx.x;
    int tid = threadIdx.x;
    __shared__ float sc[5];
    if (tid < 5) {
        float a = ltr_b[0];
        const float* pp = partial + (b * 5 + tid) * NCHUNK;
#pragma unroll
        for (int ch = 0; ch < NCHUNK; ++ch) a += pp[ch];
        sc[tid] = a;
    }
    __syncthreads();
    if (tid < 5) {
        float m = fmaxf(fmaxf(fmaxf(sc[0], sc[1]), fmaxf(sc[2], sc[3])), sc[4]);
        float sum = 0.f;
#pragma unroll
        for (int i = 0; i < 5; ++i) sum += __expf(sc[i] - m);
        out[b * 5 + tid] = sc[tid] - m - __logf(sum);
    }
}

extern "C" void kernel_launch(void* const* d_in, const int* in_sizes, int n_in,
                              void* d_out, int out_size, void* d_ws, size_t ws_size,
                              hipStream_t stream)
{
    const int*   cand = (const int*)d_in[0];
    const int*   clk  = (const int*)d_in[1];
    const float* cpad = (const float*)d_in[2];
    const float* hpad = (const float*)d_in[3];
    const float* emb  = (const float*)d_in[4];
    const float* lw   = (const float*)d_in[5];
    const float* lb   = (const float*)d_in[6];
    float* out = (float*)d_out;

    _Float16* wsH  = (_Float16*)d_ws;                                                    // 22.528 MB
    float* partial = (float*)((char*)d_ws + (size_t)(NROW_CDD + NROW_HIS) * KP * 2);     // 16 KB

    hipLaunchKernelGGL(gather_norm, dim3((NROW_CDD + NROW_HIS) / 4), dim3(256), 0, stream,
                       cand, clk, emb, wsH);
    hipLaunchKernelGGL(knrm_fused, dim3(NCHUNK, B_), dim3(256), 0, stream,
                       wsH, cpad, hpad, lw, partial);
    hipLaunchKernelGGL(finalize, dim3(B_), dim3(64), 0, stream, partial, lb, out);
}

// Round 5
// 53.466 us; speedup vs baseline: 1.3439x; 1.0242x over previous
//
#include <hip/hip_runtime.h>
#include <hip/hip_fp16.h>

typedef _Float16 half8 __attribute__((ext_vector_type(8)));
typedef float float4v __attribute__((ext_vector_type(4)));

#define E_DIM 300
#define KP 320               // padded K (10 MFMA k-steps of 32)
#define B_ 32
#define NROW_CDD 3200        // 32*5*20
#define NROW_HIS 32000       // 32*50*20
#define NCHUNK 25            // 2 h per chunk, 40 his rows

// ---------------- Kernel 1: gather + l2-normalize -> fp16 rows (K padded to 320) --------
__global__ __launch_bounds__(256) void gather_norm(const int* __restrict__ cand,
                                                   const int* __restrict__ clk,
                                                   const float* __restrict__ emb,
                                                   _Float16* __restrict__ outH)
{
    int row  = blockIdx.x * 4 + (threadIdx.x >> 6);
    int lane = threadIdx.x & 63;
    int tok = (row < NROW_CDD) ? cand[row] : clk[row - NROW_CDD];
    const float* e = emb + (long)tok * E_DIM;
    float v[5];
    float ss = 0.f;
#pragma unroll
    for (int j = 0; j < 5; ++j) {
        int idx = lane + j * 64;
        float x = (idx < E_DIM) ? e[idx] : 0.f;
        v[j] = x;
        ss += x * x;
    }
#pragma unroll
    for (int off = 32; off; off >>= 1) ss += __shfl_xor(ss, off);
    float scale = 1.0f / fmaxf(sqrtf(ss), 1e-12f);
    _Float16* o = outH + (long)row * KP;
#pragma unroll
    for (int j = 0; j < 5; ++j) {
        int idx = lane + j * 64;
        o[idx] = (_Float16)((idx < E_DIM) ? v[j] * scale : 0.f);
    }
}

// ---------------- Kernel 2: fused sim-GEMM + gaussian pooling ---------------------------
// grid (25, 32) = 800 blocks, 256 threads. LDS ~35.6 KB -> 4 blocks/CU, grid fully resident.
// B chunk staged once to LDS (k-major, conflict-free); A fragments direct from global (L2-hot).
__global__ __launch_bounds__(256) void knrm_fused(const _Float16* __restrict__ wsH,
                                                  const float* __restrict__ cpad,
                                                  const float* __restrict__ hpad,
                                                  const float* __restrict__ ltr_w,
                                                  float* __restrict__ partial)
{
    __shared__ __align__(16) char Bs[40 * 10 * 64 + 512];   // (k*40+r)*64 + g*16, +guard
    __shared__ _Float16 simH[100 * 42];                     // sim tile fp16, stride 42
    __shared__ float hpS[40];
    __shared__ float wvS[40];
    __shared__ float svals[200];

    int b = blockIdx.y, chunk = blockIdx.x;
    int tid = threadIdx.x;
    int wave = tid >> 6, lane = tid & 63;
    int g = lane >> 4, r16 = lane & 15;

    if (tid < 40) {
        hpS[tid] = hpad[b * 1000 + chunk * 40 + tid];
        wvS[tid] = ltr_w[chunk * 40 + tid];
    }

    const char* gA = (const char*)(wsH + (size_t)b * 100 * KP);
    const char* gB = (const char*)(wsH + (size_t)NROW_CDD * KP + (size_t)b * 1000 * KP);

    // ---- stage B chunk (40 rows x 640 B) into LDS, k-major, coalesced & conflict-free ----
    for (int u = tid; u < 1600; u += 256) {
        int k = u / 160, rem = u - k * 160;
        int r = rem >> 2, gg = rem & 3;
        int gr = chunk * 40 + r; if (gr > 999) gr = 999;
        *(uint4*)(Bs + (size_t)(k * 40 + r) * 64 + gg * 16) =
            *(const uint4*)(gB + (size_t)gr * 640 + k * 64 + gg * 16);
    }
    __syncthreads();

    // ---- Phase 1: 100x40 sim tile via MFMA (B from LDS, A from global) ----
    float4v acc[2][3];
#pragma unroll
    for (int mi = 0; mi < 2; ++mi)
#pragma unroll
        for (int n = 0; n < 3; ++n) acc[mi][n] = (float4v){0.f, 0.f, 0.f, 0.f};

#pragma unroll 2
    for (int k = 0; k < 10; ++k) {
        half8 bf[3];
#pragma unroll
        for (int n = 0; n < 3; ++n)
            bf[n] = *(const half8*)(Bs + (size_t)(k * 40 + n * 16 + r16) * 64 + g * 16);
#pragma unroll
        for (int mi = 0; mi < 2; ++mi) {
            int m = wave * 2 + mi;
            if (m < 7) {
                int rA = m * 16 + r16; if (rA > 99) rA = 99;
                half8 af = *(const half8*)(gA + (size_t)rA * 640 + k * 64 + g * 16);
#pragma unroll
                for (int n = 0; n < 3; ++n)
                    acc[mi][n] = __builtin_amdgcn_mfma_f32_16x16x32_f16(af, bf[n], acc[mi][n], 0, 0, 0);
            }
        }
    }
    // C/D layout (m89-verified): col = lane&15 (B-row), row = (lane>>4)*4+j (A-row)
#pragma unroll
    for (int mi = 0; mi < 2; ++mi) {
        int m = wave * 2 + mi;
        if (m < 7) {
#pragma unroll
            for (int n = 0; n < 3; ++n) {
                int col = n * 16 + r16;
                if (col < 40) {
#pragma unroll
                    for (int j = 0; j < 4; ++j) {
                        int row = m * 16 + g * 4 + j;
                        if (row < 100) simH[row * 42 + col] = (_Float16)acc[mi][n][j];
                    }
                }
            }
        }
    }
    __syncthreads();

    // ---- Phase 2: gaussian kernels + log pooling (fast intrinsics, psum[20] static) ----
    int unit_h = tid / 100;          // 0 or 1 (for tid<200)
    int row = tid - unit_h * 100;

    if (tid < 200) {
        float psum[20];
#pragma unroll
        for (int k = 0; k < 20; ++k) psum[k] = 0.f;

        const _Float16* sp = simH + row * 42 + unit_h * 20;
        const float* mp = hpS + unit_h * 20;
#pragma unroll 4
        for (int t = 0; t < 20; ++t) {
            float s  = (float)sp[t];
            float mm = mp[t];
            float a  = -50.0f * s * s;     // -1/(2*0.1^2) = -50
#pragma unroll
            for (int k = 0; k < 19; ++k) {
                const float mu = -0.9f + 0.1f * (float)k;
                const float bk = 100.0f * mu;      // 2*50*mu
                const float ck = -50.0f * mu * mu;
                float arg = fmaf(bk, s, a + ck);   // -50(s-mu)^2
                psum[k] = fmaf(__expf(arg), mm, psum[k]);
            }
            float d = s - 1.0f;
            psum[19] = fmaf(__expf(-500000.0f * d * d), mm, psum[19]);
        }
        float val = 0.f;
#pragma unroll
        for (int k = 0; k < 20; ++k)
            val += __logf(fmaxf(psum[k], 1e-10f)) * wvS[unit_h * 20 + k];
        val *= 0.01f * cpad[b * 100 + row];
        svals[row * 2 + unit_h] = val;
    }
    __syncthreads();

    // ---- per-candidate partial for this chunk ----
    if (tid < 5) {
        float ssum = 0.f;
#pragma unroll
        for (int i = 0; i < 40; ++i) ssum += svals[tid * 40 + i];
        partial[(b * 5 + tid) * NCHUNK + chunk] = ssum;
    }
}

// ---------------- Kernel 3: sum chunks + bias + log_softmax over C=5 --------------------
__global__ __launch_bounds__(64) void finalize(const float* __restrict__ partial,
                                               const float* __restrict__ ltr_b,
                                               float* __restrict__ out)
{
    int b = blockIdx.x;
    int tid = threadIdx.x;
    __shared__ float sc[5];
    if (tid < 5) {
        float a = ltr_b[0];
        const float* pp = partial + (b * 5 + tid) * NCHUNK;
#pragma unroll
        for (int ch = 0; ch < NCHUNK; ++ch) a += pp[ch];
        sc[tid] = a;
    }
    __syncthreads();
    if (tid < 5) {
        float m = fmaxf(fmaxf(fmaxf(sc[0], sc[1]), fmaxf(sc[2], sc[3])), sc[4]);
        float sum = 0.f;
#pragma unroll
        for (int i = 0; i < 5; ++i) sum += __expf(sc[i] - m);
        out[b * 5 + tid] = sc[tid] - m - __logf(sum);
    }
}

extern "C" void kernel_launch(void* const* d_in, const int* in_sizes, int n_in,
                              void* d_out, int out_size, void* d_ws, size_t ws_size,
                              hipStream_t stream)
{
    const int*   cand = (const int*)d_in[0];
    const int*   clk  = (const int*)d_in[1];
    const float* cpad = (const float*)d_in[2];
    const float* hpad = (const float*)d_in[3];
    const float* emb  = (const float*)d_in[4];
    const float* lw   = (const float*)d_in[5];
    const float* lb   = (const float*)d_in[6];
    float* out = (float*)d_out;

    _Float16* wsH  = (_Float16*)d_ws;                                                    // 22.528 MB
    float* partial = (float*)((char*)d_ws + (size_t)(NROW_CDD + NROW_HIS) * KP * 2);     // 16 KB

    hipLaunchKernelGGL(gather_norm, dim3((NROW_CDD + NROW_HIS) / 4), dim3(256), 0, stream,
                       cand, clk, emb, wsH);
    hipLaunchKernelGGL(knrm_fused, dim3(NCHUNK, B_), dim3(256), 0, stream,
                       wsH, cpad, hpad, lw, partial);
    hipLaunchKernelGGL(finalize, dim3(B_), dim3(64), 0, stream, partial, lb, out);
}